// Round 7
// baseline (357.902 us; speedup 1.0000x reference)
//
#include <hip/hip_runtime.h>
#include <hip/hip_fp16.h>

// ---------------------------------------------------------------------------
// HypergraphNet: out = conv2(relu(conv1(x)))
// conv(x) = D^-1 H diag(w) B^-1 H^T (x @ W) + b
// N = E = 65536, F = 128, nnz = 2^20.
//
// Round-16b: R12 structure + non-temporal scattered src loads (no L1
// allocate). R16 failed to compile: __builtin_nontemporal_load rejects
// HIP_vector_type (uint4); use ext_vector_type(4) of uint instead.
//   * Evidence for nt: gather rate ~6 TB/s logical is invariant to
//     occupancy (R11), ILP (R12), L2-vs-HBM residency (R13: FETCH /5.6,
//     time unchanged) -> suspected wall is L1 miss-fill processing, which
//     both L2-hit and HBM paths share. Random loads have ~0% L1 hit
//     (16 MB set vs 32 KB L1), so nt is free if theory is wrong.
//   * u16 col, unroll-8 gather kept (R12 verified).
// Launches (7): prep_w, passB, passC+GEMM1, gatherE1, gatherN1+GEMM2,
//               gatherE2, gatherN2
// ---------------------------------------------------------------------------

typedef unsigned int uint32;
typedef unsigned short u16;
typedef _Float16 f16;
typedef _Float16 f16x8 __attribute__((ext_vector_type(8)));
typedef float f32x4 __attribute__((ext_vector_type(4)));
typedef unsigned int u32x4 __attribute__((ext_vector_type(4)));

#define NBUK 256
#define BCAP 5120   // bucket capacity; mean 4096, sigma 64 -> 16 sigma slack

__global__ __launch_bounds__(256) void k_prep_w(const float* __restrict__ W1,
                                                const float* __restrict__ W2,
                                                f16* __restrict__ W1t,
                                                f16* __restrict__ W2t,
                                                int* __restrict__ cur_e,
                                                int* __restrict__ cur_n) {
  if (blockIdx.x == 0) cur_e[threadIdx.x] = threadIdx.x * BCAP;
  if (blockIdx.x == 1) cur_n[threadIdx.x] = threadIdx.x * BCAP;
  const float* W = (blockIdx.x & 1) ? W2 : W1;
  f16* Wt = (blockIdx.x & 1) ? W2t : W1t;
  const int base = (blockIdx.x >> 1) * 4096;
#pragma unroll
  for (int it = 0; it < 16; ++it) {
    int idx = base + it * 256 + threadIdx.x;
    int k = idx >> 7, n = idx & 127;
    Wt[n * 128 + k] = (f16)W[k * 128 + n];
  }
}

// Bin entries of both sides into coarse buckets as packed records
// (keylow<<16 | value). Input read EXACTLY ONCE, cached in registers.
__global__ __launch_bounds__(256) void k_passB(const int* __restrict__ nidx,
                                               const int* __restrict__ eidx,
                                               int* __restrict__ cur_e,
                                               int* __restrict__ cur_n,
                                               uint32* __restrict__ rec_e,
                                               uint32* __restrict__ rec_n,
                                               int nnz) {
  __shared__ int hist_e[NBUK], hist_n[NBUK];
  __shared__ int gb_e[NBUK], gb_n[NBUK];
  __shared__ int lc_e[NBUK], lc_n[NBUK];
  const int tid = threadIdx.x;
  hist_e[tid] = 0;
  hist_n[tid] = 0;
  __syncthreads();
  int nk[16], ek[16];
  const int base = blockIdx.x * 4096;
#pragma unroll
  for (int it = 0; it < 16; ++it) {
    int i = base + it * 256 + tid;
    if (i < nnz) {
      nk[it] = nidx[i];
      ek[it] = eidx[i];
      atomicAdd(&hist_e[ek[it] >> 8], 1);
      atomicAdd(&hist_n[nk[it] >> 8], 1);
    } else {
      nk[it] = -1;
    }
  }
  __syncthreads();
  {
    int he = hist_e[tid], hn = hist_n[tid];
    gb_e[tid] = he ? atomicAdd(&cur_e[tid], he) : 0;
    gb_n[tid] = hn ? atomicAdd(&cur_n[tid], hn) : 0;
    lc_e[tid] = 0;
    lc_n[tid] = 0;
  }
  __syncthreads();
#pragma unroll
  for (int it = 0; it < 16; ++it) {
    if (nk[it] >= 0) {
      int de = ek[it] >> 8;
      int pe = atomicAdd(&lc_e[de], 1);
      rec_e[gb_e[de] + pe] = ((uint32)(ek[it] & 0xff) << 16) | (uint32)nk[it];
      int dn = nk[it] >> 8;
      int pn = atomicAdd(&lc_n[dn], 1);
      rec_n[gb_n[dn] + pn] = ((uint32)(nk[it] & 0xff) << 16) | (uint32)ek[it];
    }
  }
}

// Fused: blocks [0,512) finalize buckets (passC, records LDS-staged);
// blocks [512,1536) compute GEMM1: f0h = half(x @ W1) via MFMA, B direct
// from global. Independent work -> co-scheduled on the CUs.
__global__ __launch_bounds__(256) void k_passC_gemm(
    const uint32* __restrict__ rec_e, const uint32* __restrict__ rec_n,
    const int* __restrict__ cur_e, const int* __restrict__ cur_n,
    const float* __restrict__ w,
    int* __restrict__ rp_e, int* __restrict__ rp_n,
    u16* __restrict__ col_e, u16* __restrict__ col_n,
    float* __restrict__ e_scale, float* __restrict__ d_inv,
    const float* __restrict__ A, const f16* __restrict__ Bt,
    f16* __restrict__ C) {
  __shared__ __align__(16) char smem[BCAP * 4 + 4 * 256 * 4];  // 24576 B
  const int tid = threadIdx.x;

  if (blockIdx.x < 512) {
    // ---------------- passC path ----------------
    uint32* lrec = (uint32*)smem;                 // [BCAP]
    int* hist = (int*)(smem + BCAP * 4);          // [256]
    int* s = hist + 256;                          // [256]
    int* lcur = s + 256;                          // [256]
    float* degf = (float*)(lcur + 256);           // [256]
    const int side = blockIdx.x >> 8;
    const int b = blockIdx.x & 255;
    const uint32* rec = side ? rec_n : rec_e;
    const int* cur = side ? cur_n : cur_e;
    int* rp = side ? rp_n : rp_e;
    u16* col = side ? col_n : col_e;

    const int beg = b * BCAP, end = cur[b];
    const int n = end - beg;
    hist[tid] = 0;
    degf[tid] = 0.f;
    __syncthreads();
    for (int j = tid; j < n; j += 256) lrec[j] = rec[beg + j];
    __syncthreads();
    for (int j = tid; j < n; j += 256) {
      uint32 r = lrec[j];
      int d = r >> 16;
      atomicAdd(&hist[d], 1);
      if (side) atomicAdd(&degf[d], w[r & 0xffff]);
    }
    __syncthreads();
    int h = hist[tid];
    s[tid] = h;
    __syncthreads();
    for (int off = 1; off < 256; off <<= 1) {
      int t = (tid >= off) ? s[tid - off] : 0;
      __syncthreads();
      s[tid] += t;
      __syncthreads();
    }
    const int start = s[tid] - h;
    const int key = (b << 8) | tid;
    rp[b * 257 + tid] = beg + start;
    if (tid == 255) rp[b * 257 + 256] = end;
    if (side) {
      float d = degf[tid];
      d_inv[key] = d > 0.f ? 1.f / d : 0.f;
    } else {
      e_scale[key] = h > 0 ? w[key] / (float)h : 0.f;
    }
    lcur[tid] = start;
    __syncthreads();
    for (int j = tid; j < n; j += 256) {
      uint32 r = lrec[j];
      int d = r >> 16;
      int p = atomicAdd(&lcur[d], 1);
      col[beg + p] = (u16)(r & 0xffffu);
    }
  } else {
    // ---------------- GEMM1 path (A fp32, B direct from global) ----------
    f16(*As)[136] = (f16(*)[136])smem;            // [64][136] = 17408 B
    const size_t m0 = (size_t)(blockIdx.x - 512) * 64;
    {  // stage A: 4 threads/row, 32 halves each (fp32 -> f16)
      const int row = tid >> 2, seg = tid & 3;
      const float4* ap = reinterpret_cast<const float4*>(A + (m0 + row) * 128 + seg * 32);
#pragma unroll
      for (int i = 0; i < 8; ++i) {
        float4 v = ap[i];
        union { f16 h[4]; uint2 u; } pk;
        pk.h[0] = (f16)v.x; pk.h[1] = (f16)v.y;
        pk.h[2] = (f16)v.z; pk.h[3] = (f16)v.w;
        *reinterpret_cast<uint2*>(&As[row][seg * 32 + i * 4]) = pk.u;
      }
    }
    __syncthreads();
    const int wave = tid >> 6, lane = tid & 63;
    const int wm = wave >> 1, wn = wave & 1;
    const int fr = lane & 15, quad = lane >> 4;
    f32x4 acc[2][4];
#pragma unroll
    for (int i = 0; i < 2; ++i)
#pragma unroll
      for (int j = 0; j < 4; ++j) acc[i][j] = (f32x4){0.f, 0.f, 0.f, 0.f};
#pragma unroll
    for (int kk = 0; kk < 4; ++kk) {
      f16x8 af[2], bf[4];
#pragma unroll
      for (int i = 0; i < 2; ++i)
        af[i] = *reinterpret_cast<const f16x8*>(&As[wm * 32 + i * 16 + fr][kk * 32 + quad * 8]);
#pragma unroll
      for (int j = 0; j < 4; ++j)
        bf[j] = *reinterpret_cast<const f16x8*>(Bt + (wn * 64 + j * 16 + fr) * 128 + kk * 32 + quad * 8);
#pragma unroll
      for (int i = 0; i < 2; ++i)
#pragma unroll
        for (int j = 0; j < 4; ++j)
          acc[i][j] = __builtin_amdgcn_mfma_f32_16x16x32_f16(af[i], bf[j], acc[i][j], 0, 0, 0);
    }
    // C/D layout: col=lane&15, row=quad*4+reg
#pragma unroll
    for (int i = 0; i < 2; ++i)
#pragma unroll
      for (int j = 0; j < 4; ++j)
#pragma unroll
        for (int r = 0; r < 4; ++r) {
          size_t row = m0 + wm * 32 + i * 16 + quad * 4 + r;
          int colc = wn * 64 + j * 16 + fr;
          C[row * 128 + colc] = (f16)acc[i][j][r];
        }
  }
}

// Fused gatherN + GEMM: block b gathers node rows [64b, 64b+64) from src
// (e_feat) with d_inv+bias+relu, writes them as f16 into the MFMA As tile,
// then computes C[64 rows] = As @ W^T (B direct from global). h is never
// materialized to global. src reads are non-temporal (no L1 allocate).
__global__ __launch_bounds__(256) void k_gngemm(const u32x4* __restrict__ src,
                                                const int* __restrict__ rp,
                                                const u16* __restrict__ col,
                                                const float* __restrict__ d_inv,
                                                const float* __restrict__ bias,
                                                const f16* __restrict__ Bt,
                                                f16* __restrict__ C) {
  __shared__ f16 As[64][136];
  const int tid = threadIdx.x;
  const int b = blockIdx.x;
  const int g = tid >> 4, l = tid & 15;

  // ---- gather phase: 4 passes x 16 rows ----
  union U { u32x4 u; f16 h[8]; };
#pragma unroll
  for (int p = 0; p < 4; ++p) {
    const int rl = p * 16 + g;
    const int row = b * 64 + rl;
    const int bidx = (row >> 8) * 257 + (row & 255);
    const int beg = rp[bidx], end = rp[bidx + 1];
    float acc[8];
#pragma unroll
    for (int k = 0; k < 8; ++k) acc[k] = 0.f;
    int j = beg;
    for (; j + 7 < end; j += 8) {
      int c0 = col[j], c1 = col[j + 1], c2 = col[j + 2], c3 = col[j + 3];
      int c4 = col[j + 4], c5 = col[j + 5], c6 = col[j + 6], c7 = col[j + 7];
      U v0, v1, v2, v3, v4, v5, v6, v7;
      v0.u = __builtin_nontemporal_load(&src[(size_t)c0 * 16 + l]);
      v1.u = __builtin_nontemporal_load(&src[(size_t)c1 * 16 + l]);
      v2.u = __builtin_nontemporal_load(&src[(size_t)c2 * 16 + l]);
      v3.u = __builtin_nontemporal_load(&src[(size_t)c3 * 16 + l]);
      v4.u = __builtin_nontemporal_load(&src[(size_t)c4 * 16 + l]);
      v5.u = __builtin_nontemporal_load(&src[(size_t)c5 * 16 + l]);
      v6.u = __builtin_nontemporal_load(&src[(size_t)c6 * 16 + l]);
      v7.u = __builtin_nontemporal_load(&src[(size_t)c7 * 16 + l]);
#pragma unroll
      for (int k = 0; k < 8; ++k)
        acc[k] += (((float)v0.h[k] + (float)v1.h[k]) + ((float)v2.h[k] + (float)v3.h[k])) +
                  (((float)v4.h[k] + (float)v5.h[k]) + ((float)v6.h[k] + (float)v7.h[k]));
    }
    for (; j + 3 < end; j += 4) {
      int c0 = col[j], c1 = col[j + 1], c2 = col[j + 2], c3 = col[j + 3];
      U v0, v1, v2, v3;
      v0.u = __builtin_nontemporal_load(&src[(size_t)c0 * 16 + l]);
      v1.u = __builtin_nontemporal_load(&src[(size_t)c1 * 16 + l]);
      v2.u = __builtin_nontemporal_load(&src[(size_t)c2 * 16 + l]);
      v3.u = __builtin_nontemporal_load(&src[(size_t)c3 * 16 + l]);
#pragma unroll
      for (int k = 0; k < 8; ++k)
        acc[k] += ((float)v0.h[k] + (float)v1.h[k]) + ((float)v2.h[k] + (float)v3.h[k]);
    }
    for (; j < end; ++j) {
      U v;
      v.u = __builtin_nontemporal_load(&src[(size_t)col[j] * 16 + l]);
#pragma unroll
      for (int k = 0; k < 8; ++k) acc[k] += (float)v.h[k];
    }
    const float sc = d_inv[row];
    const float4* bp = reinterpret_cast<const float4*>(bias) + l * 2;
    float4 b0 = bp[0], b1 = bp[1];
    acc[0] = fmaxf(acc[0] * sc + b0.x, 0.f);
    acc[1] = fmaxf(acc[1] * sc + b0.y, 0.f);
    acc[2] = fmaxf(acc[2] * sc + b0.z, 0.f);
    acc[3] = fmaxf(acc[3] * sc + b0.w, 0.f);
    acc[4] = fmaxf(acc[4] * sc + b1.x, 0.f);
    acc[5] = fmaxf(acc[5] * sc + b1.y, 0.f);
    acc[6] = fmaxf(acc[6] * sc + b1.z, 0.f);
    acc[7] = fmaxf(acc[7] * sc + b1.w, 0.f);
    U o;
#pragma unroll
    for (int k = 0; k < 8; ++k) o.h[k] = (f16)acc[k];
    *reinterpret_cast<u32x4*>(&As[rl][l * 8]) = o.u;
  }
  __syncthreads();

  // ---- MFMA phase ----
  const int wave = tid >> 6, lane = tid & 63;
  const int wm = wave >> 1, wn = wave & 1;
  const int fr = lane & 15, quad = lane >> 4;
  const size_t m0 = (size_t)b * 64;
  f32x4 acc[2][4];
#pragma unroll
  for (int i = 0; i < 2; ++i)
#pragma unroll
    for (int j = 0; j < 4; ++j) acc[i][j] = (f32x4){0.f, 0.f, 0.f, 0.f};
#pragma unroll
  for (int kk = 0; kk < 4; ++kk) {
    f16x8 af[2], bf[4];
#pragma unroll
    for (int i = 0; i < 2; ++i)
      af[i] = *reinterpret_cast<const f16x8*>(&As[wm * 32 + i * 16 + fr][kk * 32 + quad * 8]);
#pragma unroll
    for (int j = 0; j < 4; ++j)
      bf[j] = *reinterpret_cast<const f16x8*>(Bt + (wn * 64 + j * 16 + fr) * 128 + kk * 32 + quad * 8);
#pragma unroll
    for (int i = 0; i < 2; ++i)
#pragma unroll
      for (int j = 0; j < 4; ++j)
        acc[i][j] = __builtin_amdgcn_mfma_f32_16x16x32_f16(af[i], bf[j], acc[i][j], 0, 0, 0);
  }
#pragma unroll
  for (int i = 0; i < 2; ++i)
#pragma unroll
    for (int j = 0; j < 4; ++j)
#pragma unroll
      for (int r = 0; r < 4; ++r) {
        size_t row = m0 + wm * 32 + i * 16 + quad * 4 + r;
        int colc = wn * 64 + j * 16 + fr;
        C[row * 128 + colc] = (f16)acc[i][j][r];
      }
}

// 16 lanes x 16B (half8) per output row, unroll-8 + 4 + scalar tail,
// fp32 accumulate. src reads non-temporal (no L1 allocate).
// rp layout: beg = rp[(row>>8)*257 + (row&255)], end = next entry.
__global__ __launch_bounds__(256) void k_gather(const u32x4* __restrict__ src,
                                                void* __restrict__ dst,
                                                const int* __restrict__ rp,
                                                const u16* __restrict__ col,
                                                const float* __restrict__ rscale,
                                                const float* __restrict__ bias,
                                                int relu, int out_f32, int nrows) {
  const int row = (blockIdx.x * 256 + threadIdx.x) >> 4;
  const int lane = threadIdx.x & 15;
  if (row >= nrows) return;
  const int bidx = (row >> 8) * 257 + (row & 255);
  const int beg = rp[bidx], end = rp[bidx + 1];
  float acc[8];
#pragma unroll
  for (int k = 0; k < 8; ++k) acc[k] = 0.f;
  union U { u32x4 u; f16 h[8]; };
  int j = beg;
  for (; j + 7 < end; j += 8) {
    int c0 = col[j], c1 = col[j + 1], c2 = col[j + 2], c3 = col[j + 3];
    int c4 = col[j + 4], c5 = col[j + 5], c6 = col[j + 6], c7 = col[j + 7];
    U v0, v1, v2, v3, v4, v5, v6, v7;
    v0.u = __builtin_nontemporal_load(&src[(size_t)c0 * 16 + lane]);
    v1.u = __builtin_nontemporal_load(&src[(size_t)c1 * 16 + lane]);
    v2.u = __builtin_nontemporal_load(&src[(size_t)c2 * 16 + lane]);
    v3.u = __builtin_nontemporal_load(&src[(size_t)c3 * 16 + lane]);
    v4.u = __builtin_nontemporal_load(&src[(size_t)c4 * 16 + lane]);
    v5.u = __builtin_nontemporal_load(&src[(size_t)c5 * 16 + lane]);
    v6.u = __builtin_nontemporal_load(&src[(size_t)c6 * 16 + lane]);
    v7.u = __builtin_nontemporal_load(&src[(size_t)c7 * 16 + lane]);
#pragma unroll
    for (int k = 0; k < 8; ++k)
      acc[k] += (((float)v0.h[k] + (float)v1.h[k]) + ((float)v2.h[k] + (float)v3.h[k])) +
                (((float)v4.h[k] + (float)v5.h[k]) + ((float)v6.h[k] + (float)v7.h[k]));
  }
  for (; j + 3 < end; j += 4) {
    int c0 = col[j], c1 = col[j + 1], c2 = col[j + 2], c3 = col[j + 3];
    U v0, v1, v2, v3;
    v0.u = __builtin_nontemporal_load(&src[(size_t)c0 * 16 + lane]);
    v1.u = __builtin_nontemporal_load(&src[(size_t)c1 * 16 + lane]);
    v2.u = __builtin_nontemporal_load(&src[(size_t)c2 * 16 + lane]);
    v3.u = __builtin_nontemporal_load(&src[(size_t)c3 * 16 + lane]);
#pragma unroll
    for (int k = 0; k < 8; ++k)
      acc[k] += ((float)v0.h[k] + (float)v1.h[k]) + ((float)v2.h[k] + (float)v3.h[k]);
  }
  for (; j < end; ++j) {
    U v;
    v.u = __builtin_nontemporal_load(&src[(size_t)col[j] * 16 + lane]);
#pragma unroll
    for (int k = 0; k < 8; ++k) acc[k] += (float)v.h[k];
  }
  const float s = rscale[row];
#pragma unroll
  for (int k = 0; k < 8; ++k) acc[k] *= s;
  if (bias) {
    const float4* bp = reinterpret_cast<const float4*>(bias) + lane * 2;
    float4 b0 = bp[0], b1 = bp[1];
    acc[0] += b0.x; acc[1] += b0.y; acc[2] += b0.z; acc[3] += b0.w;
    acc[4] += b1.x; acc[5] += b1.y; acc[6] += b1.z; acc[7] += b1.w;
    if (relu) {
#pragma unroll
      for (int k = 0; k < 8; ++k) acc[k] = fmaxf(acc[k], 0.f);
    }
  }
  if (out_f32) {
    float4* dp = (float4*)dst + (size_t)row * 32 + lane * 2;
    dp[0] = make_float4(acc[0], acc[1], acc[2], acc[3]);
    dp[1] = make_float4(acc[4], acc[5], acc[6], acc[7]);
  } else {
    U o;
#pragma unroll
    for (int k = 0; k < 8; ++k) o.h[k] = (f16)acc[k];
    ((u32x4*)dst)[(size_t)row * 16 + lane] = o.u;
  }
}

extern "C" void kernel_launch(void* const* d_in, const int* in_sizes, int n_in,
                              void* d_out, int out_size, void* d_ws, size_t ws_size,
                              hipStream_t stream) {
  const float* x  = (const float*)d_in[0];
  const int* nidx = (const int*)d_in[1];
  const int nnz   = in_sizes[1] / 2;
  const int* eidx = nidx + nnz;
  const float* w  = (const float*)d_in[2];
  const float* W1 = (const float*)d_in[3];
  const float* b1 = (const float*)d_in[4];
  const float* W2 = (const float*)d_in[5];
  const float* b2 = (const float*)d_in[6];
  float* out = (float*)d_out;

  const int N = in_sizes[0] / 128;  // 65536 nodes
  const int E = in_sizes[2];        // 65536 edges
  const size_t NB = (size_t)N * 128;
  const size_t RCAP = (size_t)NBUK * BCAP;  // 1310720 slots per side

  // workspace layout (no aliasing anywhere)
  f16* f0h       = (f16*)d_ws;              // [N,128] half feature buf A
  f16* f1h       = f0h + NB;                // [N,128] half feature buf B
  float* d_inv   = (float*)(f1h + NB);      // [N]
  float* e_scale = d_inv + N;               // [E]
  int* rp_e      = (int*)(e_scale + E);     // [256*257]
  int* rp_n      = rp_e + NBUK * 257;       // [256*257]
  u16* col_e     = (u16*)(rp_n + NBUK * 257);  // [RCAP] u16
  u16* col_n     = col_e + RCAP;            // [RCAP] u16
  int* cur_e     = (int*)(col_n + RCAP);    // [256]
  int* cur_n     = cur_e + 256;             // [256]
  f16* W1t       = (f16*)(cur_n + 256);     // [128,128] half W1^T
  f16* W2t       = W1t + 128 * 128;         // [128,128] half W2^T
  uint32* rec_e  = (uint32*)(W2t + 128 * 128);  // [RCAP] dedicated
  uint32* rec_n  = rec_e + RCAP;                // [RCAP] dedicated

  const int ga_grid = (N * 16) / 256;  // N == E

  // ---- build ----
  k_prep_w<<<8, 256, 0, stream>>>(W1, W2, W1t, W2t, cur_e, cur_n);
  k_passB<<<(nnz + 4095) / 4096, 256, 0, stream>>>(nidx, eidx, cur_e, cur_n,
                                                   rec_e, rec_n, nnz);
  // passC (512 blocks) + GEMM1 (1024 blocks): f0h = half(x@W1)
  k_passC_gemm<<<1536, 256, 0, stream>>>(rec_e, rec_n, cur_e, cur_n, w,
                                         rp_e, rp_n, col_e, col_n,
                                         e_scale, d_inv, x, W1t, f0h);

  // ---- layer 1 + GEMM2 ----
  k_gather<<<ga_grid, 256, 0, stream>>>((const u32x4*)f0h, f1h, rp_e, col_e,
                                        e_scale, nullptr, 0, 0, E);   // f1h = e_feat
  // gatherN1 (d_inv,b1,relu) fused with GEMM2: f0h = half(h@W2), h in LDS only
  k_gngemm<<<N / 64, 256, 0, stream>>>((const u32x4*)f1h, rp_n, col_n,
                                       d_inv, b1, W2t, f0h);

  // ---- layer 2 ----
  k_gather<<<ga_grid, 256, 0, stream>>>((const u32x4*)f0h, f1h, rp_e, col_e,
                                        e_scale, nullptr, 0, 0, E);   // f1h = e_feat
  k_gather<<<ga_grid, 256, 0, stream>>>((const u32x4*)f1h, out, rp_n, col_n,
                                        d_inv, b2, 0, 1, N);          // out (fp32)
}

// Round 8
// 295.714 us; speedup vs baseline: 1.2103x; 1.2103x over previous
//
#include <hip/hip_runtime.h>
#include <hip/hip_fp16.h>

// ---------------------------------------------------------------------------
// HypergraphNet: out = conv2(relu(conv1(x)))
// conv(x) = D^-1 H diag(w) B^-1 H^T (x @ W) + b
// N = E = 65536, F = 128, nnz = 2^20.
//
// Round-17: FULL REVERT to the best-verified kernel (R10, 296.5 us).
// Seven experiments bracketed the gather wall:
//   - occupancy 2x (R11): -  | ILP 2x (R12): +4.5% gngemm only
//   - L2-residency via XCD chunk split (R13): FETCH /5.6, time UNCHANGED
//   - degree-sorted waves (R14): - (block imbalance)
//   - LDS index staging (R15): - (serialization + occupancy)
//   - L1 bypass nt (R16): -28% (L1 was helping)
// Conclusion: random 256-B row service saturates the scattered-request
// path at ~6.1 TB/s logical (~= 6.3 TB/s achievable stream ceiling),
// invariant to data residency -> architectural wall for this access
// pattern. This kernel is the measured optimum of the explored space.
// Launches (7): prep_w, passB, passC+GEMM1, gatherE1, gatherN1+GEMM2,
//               gatherE2, gatherN2
// ---------------------------------------------------------------------------

typedef unsigned int uint32;
typedef _Float16 f16;
typedef _Float16 f16x8 __attribute__((ext_vector_type(8)));
typedef float f32x4 __attribute__((ext_vector_type(4)));

#define NBUK 256
#define BCAP 5120   // bucket capacity; mean 4096, sigma 64 -> 16 sigma slack

__global__ __launch_bounds__(256) void k_prep_w(const float* __restrict__ W1,
                                                const float* __restrict__ W2,
                                                f16* __restrict__ W1t,
                                                f16* __restrict__ W2t,
                                                int* __restrict__ cur_e,
                                                int* __restrict__ cur_n) {
  if (blockIdx.x == 0) cur_e[threadIdx.x] = threadIdx.x * BCAP;
  if (blockIdx.x == 1) cur_n[threadIdx.x] = threadIdx.x * BCAP;
  const float* W = (blockIdx.x & 1) ? W2 : W1;
  f16* Wt = (blockIdx.x & 1) ? W2t : W1t;
  const int base = (blockIdx.x >> 1) * 4096;
#pragma unroll
  for (int it = 0; it < 16; ++it) {
    int idx = base + it * 256 + threadIdx.x;
    int k = idx >> 7, n = idx & 127;
    Wt[n * 128 + k] = (f16)W[k * 128 + n];
  }
}

// Bin entries of both sides into coarse buckets as packed records
// (keylow<<16 | value). Input read EXACTLY ONCE, cached in registers.
__global__ __launch_bounds__(256) void k_passB(const int* __restrict__ nidx,
                                               const int* __restrict__ eidx,
                                               int* __restrict__ cur_e,
                                               int* __restrict__ cur_n,
                                               uint32* __restrict__ rec_e,
                                               uint32* __restrict__ rec_n,
                                               int nnz) {
  __shared__ int hist_e[NBUK], hist_n[NBUK];
  __shared__ int gb_e[NBUK], gb_n[NBUK];
  __shared__ int lc_e[NBUK], lc_n[NBUK];
  const int tid = threadIdx.x;
  hist_e[tid] = 0;
  hist_n[tid] = 0;
  __syncthreads();
  int nk[16], ek[16];
  const int base = blockIdx.x * 4096;
#pragma unroll
  for (int it = 0; it < 16; ++it) {
    int i = base + it * 256 + tid;
    if (i < nnz) {
      nk[it] = nidx[i];
      ek[it] = eidx[i];
      atomicAdd(&hist_e[ek[it] >> 8], 1);
      atomicAdd(&hist_n[nk[it] >> 8], 1);
    } else {
      nk[it] = -1;
    }
  }
  __syncthreads();
  {
    int he = hist_e[tid], hn = hist_n[tid];
    gb_e[tid] = he ? atomicAdd(&cur_e[tid], he) : 0;
    gb_n[tid] = hn ? atomicAdd(&cur_n[tid], hn) : 0;
    lc_e[tid] = 0;
    lc_n[tid] = 0;
  }
  __syncthreads();
#pragma unroll
  for (int it = 0; it < 16; ++it) {
    if (nk[it] >= 0) {
      int de = ek[it] >> 8;
      int pe = atomicAdd(&lc_e[de], 1);
      rec_e[gb_e[de] + pe] = ((uint32)(ek[it] & 0xff) << 16) | (uint32)nk[it];
      int dn = nk[it] >> 8;
      int pn = atomicAdd(&lc_n[dn], 1);
      rec_n[gb_n[dn] + pn] = ((uint32)(nk[it] & 0xff) << 16) | (uint32)ek[it];
    }
  }
}

// Fused: blocks [0,512) finalize buckets (passC, records staged in LDS);
// blocks [512,1536) compute GEMM1: f0h = half(x @ W1) via MFMA, B direct
// from global. Independent work -> co-scheduled on the CUs.
__global__ __launch_bounds__(256) void k_passC_gemm(
    const uint32* __restrict__ rec_e, const uint32* __restrict__ rec_n,
    const int* __restrict__ cur_e, const int* __restrict__ cur_n,
    const float* __restrict__ w,
    int* __restrict__ rp_e, int* __restrict__ rp_n,
    uint32* __restrict__ col_e, uint32* __restrict__ col_n,
    float* __restrict__ e_scale, float* __restrict__ d_inv,
    const float* __restrict__ A, const f16* __restrict__ Bt,
    f16* __restrict__ C) {
  __shared__ __align__(16) char smem[BCAP * 4 + 4 * 256 * 4];  // 24576 B
  const int tid = threadIdx.x;

  if (blockIdx.x < 512) {
    // ---------------- passC path ----------------
    uint32* lrec = (uint32*)smem;                 // [BCAP]
    int* hist = (int*)(smem + BCAP * 4);          // [256]
    int* s = hist + 256;                          // [256]
    int* lcur = s + 256;                          // [256]
    float* degf = (float*)(lcur + 256);           // [256]
    const int side = blockIdx.x >> 8;
    const int b = blockIdx.x & 255;
    const uint32* rec = side ? rec_n : rec_e;
    const int* cur = side ? cur_n : cur_e;
    int* rp = side ? rp_n : rp_e;
    uint32* col = side ? col_n : col_e;

    const int beg = b * BCAP, end = cur[b];
    const int n = end - beg;
    hist[tid] = 0;
    degf[tid] = 0.f;
    __syncthreads();
    for (int j = tid; j < n; j += 256) lrec[j] = rec[beg + j];
    __syncthreads();
    for (int j = tid; j < n; j += 256) {
      uint32 r = lrec[j];
      int d = r >> 16;
      atomicAdd(&hist[d], 1);
      if (side) atomicAdd(&degf[d], w[r & 0xffff]);
    }
    __syncthreads();
    int h = hist[tid];
    s[tid] = h;
    __syncthreads();
    for (int off = 1; off < 256; off <<= 1) {
      int t = (tid >= off) ? s[tid - off] : 0;
      __syncthreads();
      s[tid] += t;
      __syncthreads();
    }
    const int start = s[tid] - h;
    const int key = (b << 8) | tid;
    rp[b * 257 + tid] = beg + start;
    if (tid == 255) rp[b * 257 + 256] = end;
    if (side) {
      float d = degf[tid];
      d_inv[key] = d > 0.f ? 1.f / d : 0.f;
    } else {
      e_scale[key] = h > 0 ? w[key] / (float)h : 0.f;
    }
    lcur[tid] = start;
    __syncthreads();
    for (int j = tid; j < n; j += 256) {
      uint32 r = lrec[j];
      int d = r >> 16;
      int p = atomicAdd(&lcur[d], 1);
      col[beg + p] = r & 0xffffu;
    }
  } else {
    // ---------------- GEMM1 path (A fp32, B direct from global) ----------
    f16(*As)[136] = (f16(*)[136])smem;            // [64][136] = 17408 B
    const size_t m0 = (size_t)(blockIdx.x - 512) * 64;
    {  // stage A: 4 threads/row, 32 halves each (fp32 -> f16)
      const int row = tid >> 2, seg = tid & 3;
      const float4* ap = reinterpret_cast<const float4*>(A + (m0 + row) * 128 + seg * 32);
#pragma unroll
      for (int i = 0; i < 8; ++i) {
        float4 v = ap[i];
        union { f16 h[4]; uint2 u; } pk;
        pk.h[0] = (f16)v.x; pk.h[1] = (f16)v.y;
        pk.h[2] = (f16)v.z; pk.h[3] = (f16)v.w;
        *reinterpret_cast<uint2*>(&As[row][seg * 32 + i * 4]) = pk.u;
      }
    }
    __syncthreads();
    const int wave = tid >> 6, lane = tid & 63;
    const int wm = wave >> 1, wn = wave & 1;
    const int fr = lane & 15, quad = lane >> 4;
    f32x4 acc[2][4];
#pragma unroll
    for (int i = 0; i < 2; ++i)
#pragma unroll
      for (int j = 0; j < 4; ++j) acc[i][j] = (f32x4){0.f, 0.f, 0.f, 0.f};
#pragma unroll
    for (int kk = 0; kk < 4; ++kk) {
      f16x8 af[2], bf[4];
#pragma unroll
      for (int i = 0; i < 2; ++i)
        af[i] = *reinterpret_cast<const f16x8*>(&As[wm * 32 + i * 16 + fr][kk * 32 + quad * 8]);
#pragma unroll
      for (int j = 0; j < 4; ++j)
        bf[j] = *reinterpret_cast<const f16x8*>(Bt + (wn * 64 + j * 16 + fr) * 128 + kk * 32 + quad * 8);
#pragma unroll
      for (int i = 0; i < 2; ++i)
#pragma unroll
        for (int j = 0; j < 4; ++j)
          acc[i][j] = __builtin_amdgcn_mfma_f32_16x16x32_f16(af[i], bf[j], acc[i][j], 0, 0, 0);
    }
    // C/D layout: col=lane&15, row=quad*4+reg
#pragma unroll
    for (int i = 0; i < 2; ++i)
#pragma unroll
      for (int j = 0; j < 4; ++j)
#pragma unroll
        for (int r = 0; r < 4; ++r) {
          size_t row = m0 + wm * 32 + i * 16 + quad * 4 + r;
          int colc = wn * 64 + j * 16 + fr;
          C[row * 128 + colc] = (f16)acc[i][j][r];
        }
  }
}

// Fused gatherN + GEMM: block b gathers node rows [64b, 64b+64) from src
// (e_feat) with d_inv+bias+relu, writes them as f16 into the MFMA As tile,
// then computes C[64 rows] = As @ W^T (B direct from global). h is never
// materialized to global.
__global__ __launch_bounds__(256) void k_gngemm(const uint4* __restrict__ src,
                                                const int* __restrict__ rp,
                                                const uint32* __restrict__ col,
                                                const float* __restrict__ d_inv,
                                                const float* __restrict__ bias,
                                                const f16* __restrict__ Bt,
                                                f16* __restrict__ C) {
  __shared__ f16 As[64][136];
  const int tid = threadIdx.x;
  const int b = blockIdx.x;
  const int g = tid >> 4, l = tid & 15;

  // ---- gather phase: 4 passes x 16 rows ----
  union U { uint4 u; f16 h[8]; };
#pragma unroll
  for (int p = 0; p < 4; ++p) {
    const int rl = p * 16 + g;
    const int row = b * 64 + rl;
    const int bidx = (row >> 8) * 257 + (row & 255);
    const int beg = rp[bidx], end = rp[bidx + 1];
    float acc[8];
#pragma unroll
    for (int k = 0; k < 8; ++k) acc[k] = 0.f;
    int j = beg;
    for (; j + 3 < end; j += 4) {
      uint32 c0 = col[j], c1 = col[j + 1], c2 = col[j + 2], c3 = col[j + 3];
      U v0, v1, v2, v3;
      v0.u = src[(size_t)c0 * 16 + l];
      v1.u = src[(size_t)c1 * 16 + l];
      v2.u = src[(size_t)c2 * 16 + l];
      v3.u = src[(size_t)c3 * 16 + l];
#pragma unroll
      for (int k = 0; k < 8; ++k)
        acc[k] += ((float)v0.h[k] + (float)v1.h[k]) + ((float)v2.h[k] + (float)v3.h[k]);
    }
    for (; j < end; ++j) {
      U v;
      v.u = src[(size_t)col[j] * 16 + l];
#pragma unroll
      for (int k = 0; k < 8; ++k) acc[k] += (float)v.h[k];
    }
    const float sc = d_inv[row];
    const float4* bp = reinterpret_cast<const float4*>(bias) + l * 2;
    float4 b0 = bp[0], b1 = bp[1];
    acc[0] = fmaxf(acc[0] * sc + b0.x, 0.f);
    acc[1] = fmaxf(acc[1] * sc + b0.y, 0.f);
    acc[2] = fmaxf(acc[2] * sc + b0.z, 0.f);
    acc[3] = fmaxf(acc[3] * sc + b0.w, 0.f);
    acc[4] = fmaxf(acc[4] * sc + b1.x, 0.f);
    acc[5] = fmaxf(acc[5] * sc + b1.y, 0.f);
    acc[6] = fmaxf(acc[6] * sc + b1.z, 0.f);
    acc[7] = fmaxf(acc[7] * sc + b1.w, 0.f);
    U o;
#pragma unroll
    for (int k = 0; k < 8; ++k) o.h[k] = (f16)acc[k];
    *reinterpret_cast<uint4*>(&As[rl][l * 8]) = o.u;
  }
  __syncthreads();

  // ---- MFMA phase ----
  const int wave = tid >> 6, lane = tid & 63;
  const int wm = wave >> 1, wn = wave & 1;
  const int fr = lane & 15, quad = lane >> 4;
  const size_t m0 = (size_t)b * 64;
  f32x4 acc[2][4];
#pragma unroll
  for (int i = 0; i < 2; ++i)
#pragma unroll
    for (int j = 0; j < 4; ++j) acc[i][j] = (f32x4){0.f, 0.f, 0.f, 0.f};
#pragma unroll
  for (int kk = 0; kk < 4; ++kk) {
    f16x8 af[2], bf[4];
#pragma unroll
    for (int i = 0; i < 2; ++i)
      af[i] = *reinterpret_cast<const f16x8*>(&As[wm * 32 + i * 16 + fr][kk * 32 + quad * 8]);
#pragma unroll
    for (int j = 0; j < 4; ++j)
      bf[j] = *reinterpret_cast<const f16x8*>(Bt + (wn * 64 + j * 16 + fr) * 128 + kk * 32 + quad * 8);
#pragma unroll
    for (int i = 0; i < 2; ++i)
#pragma unroll
      for (int j = 0; j < 4; ++j)
        acc[i][j] = __builtin_amdgcn_mfma_f32_16x16x32_f16(af[i], bf[j], acc[i][j], 0, 0, 0);
  }
#pragma unroll
  for (int i = 0; i < 2; ++i)
#pragma unroll
    for (int j = 0; j < 4; ++j)
#pragma unroll
      for (int r = 0; r < 4; ++r) {
        size_t row = m0 + wm * 32 + i * 16 + quad * 4 + r;
        int colc = wn * 64 + j * 16 + fr;
        C[row * 128 + colc] = (f16)acc[i][j][r];
      }
}

// 16 lanes x 16B (half8) per output row, unroll-4, fp32 accumulate.
// rp layout: beg = rp[(row>>8)*257 + (row&255)], end = next entry.
__global__ __launch_bounds__(256) void k_gather(const uint4* __restrict__ src,
                                                void* __restrict__ dst,
                                                const int* __restrict__ rp,
                                                const uint32* __restrict__ col,
                                                const float* __restrict__ rscale,
                                                const float* __restrict__ bias,
                                                int relu, int out_f32, int nrows) {
  const int row = (blockIdx.x * 256 + threadIdx.x) >> 4;
  const int lane = threadIdx.x & 15;
  if (row >= nrows) return;
  const int bidx = (row >> 8) * 257 + (row & 255);
  const int beg = rp[bidx], end = rp[bidx + 1];
  float acc[8];
#pragma unroll
  for (int k = 0; k < 8; ++k) acc[k] = 0.f;
  union U { uint4 u; f16 h[8]; };
  int j = beg;
  for (; j + 3 < end; j += 4) {
    uint32 c0 = col[j], c1 = col[j + 1], c2 = col[j + 2], c3 = col[j + 3];
    U v0, v1, v2, v3;
    v0.u = src[(size_t)c0 * 16 + lane];
    v1.u = src[(size_t)c1 * 16 + lane];
    v2.u = src[(size_t)c2 * 16 + lane];
    v3.u = src[(size_t)c3 * 16 + lane];
#pragma unroll
    for (int k = 0; k < 8; ++k)
      acc[k] += ((float)v0.h[k] + (float)v1.h[k]) + ((float)v2.h[k] + (float)v3.h[k]);
  }
  for (; j < end; ++j) {
    U v;
    v.u = src[(size_t)col[j] * 16 + lane];
#pragma unroll
    for (int k = 0; k < 8; ++k) acc[k] += (float)v.h[k];
  }
  const float s = rscale[row];
#pragma unroll
  for (int k = 0; k < 8; ++k) acc[k] *= s;
  if (bias) {
    const float4* bp = reinterpret_cast<const float4*>(bias) + lane * 2;
    float4 b0 = bp[0], b1 = bp[1];
    acc[0] += b0.x; acc[1] += b0.y; acc[2] += b0.z; acc[3] += b0.w;
    acc[4] += b1.x; acc[5] += b1.y; acc[6] += b1.z; acc[7] += b1.w;
    if (relu) {
#pragma unroll
      for (int k = 0; k < 8; ++k) acc[k] = fmaxf(acc[k], 0.f);
    }
  }
  if (out_f32) {
    float4* dp = (float4*)dst + (size_t)row * 32 + lane * 2;
    dp[0] = make_float4(acc[0], acc[1], acc[2], acc[3]);
    dp[1] = make_float4(acc[4], acc[5], acc[6], acc[7]);
  } else {
    U o;
#pragma unroll
    for (int k = 0; k < 8; ++k) o.h[k] = (f16)acc[k];
    ((uint4*)dst)[(size_t)row * 16 + lane] = o.u;
  }
}

extern "C" void kernel_launch(void* const* d_in, const int* in_sizes, int n_in,
                              void* d_out, int out_size, void* d_ws, size_t ws_size,
                              hipStream_t stream) {
  const float* x  = (const float*)d_in[0];
  const int* nidx = (const int*)d_in[1];
  const int nnz   = in_sizes[1] / 2;
  const int* eidx = nidx + nnz;
  const float* w  = (const float*)d_in[2];
  const float* W1 = (const float*)d_in[3];
  const float* b1 = (const float*)d_in[4];
  const float* W2 = (const float*)d_in[5];
  const float* b2 = (const float*)d_in[6];
  float* out = (float*)d_out;

  const int N = in_sizes[0] / 128;  // 65536 nodes
  const int E = in_sizes[2];        // 65536 edges
  const size_t NB = (size_t)N * 128;
  const size_t RCAP = (size_t)NBUK * BCAP;  // 1310720 slots per side

  // workspace layout (no aliasing anywhere)
  f16* f0h       = (f16*)d_ws;              // [N,128] half feature buf A
  f16* f1h       = f0h + NB;                // [N,128] half feature buf B
  float* d_inv   = (float*)(f1h + NB);      // [N]
  float* e_scale = d_inv + N;               // [E]
  int* rp_e      = (int*)(e_scale + E);     // [256*257]
  int* rp_n      = rp_e + NBUK * 257;       // [256*257]
  uint32* col_e  = (uint32*)(rp_n + NBUK * 257);  // [RCAP]
  uint32* col_n  = col_e + RCAP;            // [RCAP]
  int* cur_e     = (int*)(col_n + RCAP);    // [256]
  int* cur_n     = cur_e + 256;             // [256]
  f16* W1t       = (f16*)(cur_n + 256);     // [128,128] half W1^T
  f16* W2t       = W1t + 128 * 128;         // [128,128] half W2^T
  uint32* rec_e  = (uint32*)(W2t + 128 * 128);  // [RCAP] dedicated
  uint32* rec_n  = rec_e + RCAP;                // [RCAP] dedicated

  const int ga_grid = (N * 16) / 256;  // N == E

  // ---- build ----
  k_prep_w<<<8, 256, 0, stream>>>(W1, W2, W1t, W2t, cur_e, cur_n);
  k_passB<<<(nnz + 4095) / 4096, 256, 0, stream>>>(nidx, eidx, cur_e, cur_n,
                                                   rec_e, rec_n, nnz);
  // passC (512 blocks) + GEMM1 (1024 blocks): f0h = half(x@W1)
  k_passC_gemm<<<1536, 256, 0, stream>>>(rec_e, rec_n, cur_e, cur_n, w,
                                         rp_e, rp_n, col_e, col_n,
                                         e_scale, d_inv, x, W1t, f0h);

  // ---- layer 1 + GEMM2 ----
  k_gather<<<ga_grid, 256, 0, stream>>>((const uint4*)f0h, f1h, rp_e, col_e,
                                        e_scale, nullptr, 0, 0, E);   // f1h = e_feat
  // gatherN1 (d_inv,b1,relu) fused with GEMM2: f0h = half(h@W2), h in LDS only
  k_gngemm<<<N / 64, 256, 0, stream>>>((const uint4*)f1h, rp_n, col_n,
                                       d_inv, b1, W2t, f0h);

  // ---- layer 2 ----
  k_gather<<<ga_grid, 256, 0, stream>>>((const uint4*)f0h, f1h, rp_e, col_e,
                                        e_scale, nullptr, 0, 0, E);   // f1h = e_feat
  k_gather<<<ga_grid, 256, 0, stream>>>((const uint4*)f1h, out, rp_n, col_n,
                                        d_inv, b2, 0, 1, N);          // out (fp32)
}